// Round 11
// baseline (47.340 us; speedup 1.0000x reference)
//
#include <hip/hip_runtime.h>
#include <hip/hip_bf16.h>

typedef __attribute__((ext_vector_type(4))) int i32x4;

#define D 1024
#define NROWS 4096          // B
#define SCALE_U 14.426950408889634f   // (1/T) * log2(e)
#define LN2 0.69314718055994530942f
#define LSE_SHIFT 16.0f     // |u| <= 14.43 => exp2(u-16) in [2^-30.5, 2^-1.5]: no max needed
#define NCC 32              // column chunks — one 128-col block each
#define BM 128              // block tile rows/cols
#define BKE 64              // K elems (bytes) per slab = one K=64 i8 MFMA
#define NSLAB 16            // D / BKE

// ---------------- workspace layout ----------------
// zn      : 8192*1024 i8 (row-quantized unit vectors)        @ 0        (8 MiB)
// fs      : 8192 f32 row scales (SCALE_U folded into z1's)   @ 8388608  (32 KiB)
// psum    : 4096*32 f32                                      @ 8421376  (512 KiB)
// diag    : 4096 f32                                         @ 8945664  (16 KiB)
// contrib : 4096 f32                                         @ 8962048  (16 KiB)

__device__ __forceinline__ void gload16(const void* g, void* l) {
    __builtin_amdgcn_global_load_lds((const __attribute__((address_space(1))) void*)g,
                                     (__attribute__((address_space(3))) void*)l, 16, 0, 0);
}

// ---------- 1. row normalize + symmetric i8 quantize ----------
__global__ __launch_bounds__(256) void nrm_kernel(const float* __restrict__ feat,
                                                  signed char* __restrict__ zn,
                                                  float* __restrict__ fs) {
    const int row = blockIdx.x;           // 0..8191
    const int tid = threadIdx.x;          // 256, 4 floats each
    const float4 v = reinterpret_cast<const float4*>(feat + (size_t)row * D)[tid];
    float ss = v.x * v.x + v.y * v.y + v.z * v.z + v.w * v.w;
    float am = fmaxf(fmaxf(fabsf(v.x), fabsf(v.y)), fmaxf(fabsf(v.z), fabsf(v.w)));
#pragma unroll
    for (int off = 32; off > 0; off >>= 1) {
        ss += __shfl_down(ss, off);
        am = fmaxf(am, __shfl_down(am, off));
    }
    __shared__ float reds[4], redm[4];
    const int lane = tid & 63, wid = tid >> 6;
    if (lane == 0) { reds[wid] = ss; redm[wid] = am; }
    __syncthreads();
    const float tot = reds[0] + reds[1] + reds[2] + reds[3];
    const float amx = fmaxf(fmaxf(redm[0], redm[1]), fmaxf(redm[2], redm[3]));
    const float nrm = fmaxf(sqrtf(tot), 1e-8f);
    const float wmax = fmaxf(amx / nrm, 1e-12f);
    const float qs = 127.0f / (wmax * nrm);        // w_i * 127/wmax, w_i = v_i/nrm
    int q0 = (int)rintf(fminf(fmaxf(v.x * qs, -127.f), 127.f));
    int q1 = (int)rintf(fminf(fmaxf(v.y * qs, -127.f), 127.f));
    int q2 = (int)rintf(fminf(fmaxf(v.z * qs, -127.f), 127.f));
    int q3 = (int)rintf(fminf(fmaxf(v.w * qs, -127.f), 127.f));
    const int packed = (q0 & 255) | ((q1 & 255) << 8) | ((q2 & 255) << 16) | (q3 << 24);
    reinterpret_cast<int*>(zn)[(size_t)row * (D / 4) + tid] = packed;
    if (tid == 0)
        fs[row] = ((row < NROWS) ? SCALE_U : 1.0f) * wmax * (1.0f / 127.0f);
}

// ---------- 2. Gram (integer), i8 16x16x64, min-2-phase dbuf pipeline ----------
// T3 minimum recipe (m248v2): per slab, STAGE(next -> buf^1) issued FIRST, then
// ds_read+MFMA on buf, then ONE __syncthreads (its vmcnt/lgkm drain is covered
// by the compute phase). Double-buffered LDS, 32 KB -> still 4 blocks/CU.
// Paired-row LDS layout: 2 rows per 128B superrow, 8x16B chunks, swizzle
// phys = ((row&1)*4 + chunk) ^ (sr&7)  -> b128 frag reads are 2-way (free).
// Staged with pre-inverse-swizzled global source + linear gload_lds dest.
__global__ __launch_bounds__(256, 4) void gram_lse_kernel(const signed char* __restrict__ zn,
                                                          const float* __restrict__ fs,
                                                          float* __restrict__ psum,
                                                          float* __restrict__ diag) {
    __shared__ __align__(16) signed char As[2][64 * 128];   // 2 x 8 KiB (64 superrows)
    __shared__ __align__(16) signed char Bs[2][64 * 128];   // 2 x 8 KiB
    __shared__ float sbuf[BM][2];

    // XCD-aware swizzle: each XCD covers a 16-rowtile x 8-coltile region
    const int bid = blockIdx.x;            // 0..1023
    const int xcd = bid & 7, t = bid >> 3; // t: 0..127 within XCD
    const int rt = (xcd >> 2) * 16 + (t >> 3);   // 0..31
    const int cc = (xcd & 3) * 8 + (t & 7);      // 0..31

    const int tid = threadIdx.x;
    const int lane = tid & 63;
    const int wid  = tid >> 6;        // 0..3
    const int wm = wid >> 1, wn = wid & 1;
    const int l15 = lane & 15, g = lane >> 4;    // frag row/col = l15, k-quarter = g

    // ---- staging source (per-lane, inverse-swizzled) ----
    // wave-instr covers 16 rows (8 superrows, sr0 multiple of 8). lane l:
    // srl = l>>3, phys = l&7, idx = phys ^ srl, row = srl*2 + (idx>>2), chunk = idx&3
    const int srl    = lane >> 3;
    const int sidx   = (lane & 7) ^ srl;
    const int srow   = srl * 2 + (sidx >> 2);
    const int schunk = (sidx & 3) * 16;
    const signed char* gA = zn + (size_t)(rt * BM + srow) * D + schunk;
    const signed char* gB = zn + (size_t)(NROWS + cc * BM + srow) * D + schunk;

    // ---- fragment read bases (swizzled paired-row layout) ----
    // row = base + fr*16 + l15 ; sr = row>>1 ; sr&7 = l15>>1 ; idx = (l15&1)*4+g
    const int aoff = (wm * 32 + (l15 >> 1)) * 128 + ((((l15 & 1) << 2) | g) ^ (l15 >> 1)) * 16;
    const int boff = (wn * 32 + (l15 >> 1)) * 128 + ((((l15 & 1) << 2) | g) ^ (l15 >> 1)) * 16;

#define STAGE(buf, kb) do {                                                        \
    _Pragma("unroll")                                                              \
    for (int it = 0; it < 2; ++it) {                                               \
        const int r0 = wid * 2 + it;            /* 16-row group index 0..7 */      \
        gload16(gA + (size_t)(r0 * 16) * D + (size_t)(kb) * BKE, &As[buf][r0 * 1024]); \
        gload16(gB + (size_t)(r0 * 16) * D + (size_t)(kb) * BKE, &Bs[buf][r0 * 1024]); \
    } } while (0)

    i32x4 acc[4][4];
#pragma unroll
    for (int i = 0; i < 4; i++)
#pragma unroll
        for (int j = 0; j < 4; j++) acc[i][j] = (i32x4){0, 0, 0, 0};

#define COMPUTE(buf) do {                                                          \
    i32x4 b[4];                                                                    \
    _Pragma("unroll")                                                              \
    for (int fn = 0; fn < 4; ++fn)                                                 \
        b[fn] = *reinterpret_cast<const i32x4*>(&Bs[buf][boff + fn * 1024]);       \
    _Pragma("unroll")                                                              \
    for (int fr = 0; fr < 4; ++fr) {                                               \
        const i32x4 a = *reinterpret_cast<const i32x4*>(&As[buf][aoff + fr * 1024]); \
        _Pragma("unroll")                                                          \
        for (int fn = 0; fn < 4; ++fn)                                             \
            acc[fr][fn] = __builtin_amdgcn_mfma_i32_16x16x64_i8(a, b[fn], acc[fr][fn], 0, 0, 0); \
    } } while (0)

    STAGE(0, 0);
    __syncthreads();                       // prologue drain
    for (int kb = 0; kb < NSLAB - 1; ++kb) {
        const int cur = kb & 1;
        STAGE(cur ^ 1, kb + 1);            // issue next slab first: latency covered
        COMPUTE(cur);                      // ds_read + MFMA on current
        __syncthreads();                   // single barrier: drains stage, frees cur
    }
    COMPUTE((NSLAB - 1) & 1);              // epilogue slab, no prefetch
#undef STAGE
#undef COMPUTE

    // ---- epilogue: apply scales, diag on rt==cc, fused LSE partial sums ----
    // 16x16 C/D layout: col = lane&15, row = (lane>>4)*4 + reg
    float fs2[4];
#pragma unroll
    for (int fn = 0; fn < 4; ++fn)
        fs2[fn] = fs[NROWS + cc * BM + wn * 64 + fn * 16 + l15];

#pragma unroll
    for (int fr = 0; fr < 4; ++fr) {
#pragma unroll
        for (int r = 0; r < 4; ++r) {
            const int rl = wm * 64 + fr * 16 + g * 4 + r;
            const float f1 = fs[rt * BM + rl];
            float s = 0.f;
#pragma unroll
            for (int fn = 0; fn < 4; ++fn) {
                const float u = f1 * fs2[fn] * (float)acc[fr][fn][r];
                s += exp2f(u - LSE_SHIFT);
                if (rt == cc && rl == wn * 64 + fn * 16 + l15)
                    diag[rt * BM + rl] = u;
            }
#pragma unroll
            for (int off = 1; off < 16; off <<= 1) s += __shfl_xor(s, off);
            if (l15 == 0) sbuf[rl][wn] = s;
        }
    }
    __syncthreads();
    if (tid < BM) {
        psum[(size_t)(rt * BM + tid) * NCC + cc] = sbuf[tid][0] + sbuf[tid][1];
    }
}

// ---------- 3. per-row partial combine (diag precomputed in gram) ----------
__global__ __launch_bounds__(256) void rowfinal_kernel(const float* __restrict__ psum,
                                                       const float* __restrict__ diag,
                                                       float* __restrict__ contrib) {
    const int i = blockIdx.x * 256 + threadIdx.x;   // row 0..4095
    float4 ps[8];
#pragma unroll
    for (int q = 0; q < 8; ++q)
        ps[q] = reinterpret_cast<const float4*>(psum + (size_t)i * NCC)[q];
    float s = 0.f;
#pragma unroll
    for (int q = 0; q < 8; ++q) s += (ps[q].x + ps[q].y) + (ps[q].z + ps[q].w);
    contrib[i] = LSE_SHIFT + log2f(s) - diag[i];   // exp2-domain LSE minus u_ii
}

// ---------- 4. deterministic final reduce ----------
__global__ __launch_bounds__(256) void final_kernel(const float* __restrict__ contrib,
                                                    float* __restrict__ out) {
    const int tid = threadIdx.x;
    float s = 0.f;
    for (int j = tid; j < NROWS; j += 256) s += contrib[j];
#pragma unroll
    for (int off = 32; off > 0; off >>= 1) s += __shfl_down(s, off);
    __shared__ float red[4];
    const int lane = tid & 63, wid = tid >> 6;
    if (lane == 0) red[wid] = s;
    __syncthreads();
    if (tid == 0) out[0] = (red[0] + red[1] + red[2] + red[3]) * (LN2 / (float)NROWS);
}

extern "C" void kernel_launch(void* const* d_in, const int* in_sizes, int n_in,
                              void* d_out, int out_size, void* d_ws, size_t ws_size,
                              hipStream_t stream) {
    const float* feat = (const float*)d_in[0];
    signed char* zn = (signed char*)d_ws;
    float* fs      = (float*)((char*)d_ws + 8388608);
    float* psum    = (float*)((char*)d_ws + 8421376);
    float* diag    = (float*)((char*)d_ws + 8945664);
    float* contrib = (float*)((char*)d_ws + 8962048);
    float* out = (float*)d_out;

    nrm_kernel<<<8192, 256, 0, stream>>>(feat, zn, fs);
    gram_lse_kernel<<<1024, 256, 0, stream>>>(zn, fs, psum, diag);
    rowfinal_kernel<<<16, 256, 0, stream>>>(psum, diag, contrib);
    final_kernel<<<1, 256, 0, stream>>>(contrib, out);
}

// Round 12
// 43.357 us; speedup vs baseline: 1.0919x; 1.0919x over previous
//
#include <hip/hip_runtime.h>
#include <hip/hip_bf16.h>

typedef __attribute__((ext_vector_type(4))) int i32x4;

#define D 1024
#define NROWS 4096          // B
#define SCALE_U 14.426950408889634f   // (1/T) * log2(e)
#define LN2 0.69314718055994530942f
#define LSE_SHIFT 16.0f     // |u| <= 14.43 => exp2(u-16) in [2^-30.5, 2^-1.5]: no max needed
#define NCC 32              // column chunks — one 128-col block each
#define BM 128              // block tile rows/cols
#define BKB 128             // K bytes (i8 elems) per slab = two K=64 i8 MFMAs
#define NSLAB 8             // D / BKB

// ---------------- workspace layout ----------------
// zn      : 8192*1024 i8 (row-quantized unit vectors)        @ 0        (8 MiB)
// fs      : 8192 f32 row scales (SCALE_U folded into z1's)   @ 8388608  (32 KiB)
// psum    : 4096*32 f32                                      @ 8421376  (512 KiB)
// diag    : 4096 f32                                         @ 8945664  (16 KiB)
// contrib : 4096 f32                                         @ 8962048  (16 KiB)

__device__ __forceinline__ void gload16(const void* g, void* l) {
    __builtin_amdgcn_global_load_lds((const __attribute__((address_space(1))) void*)g,
                                     (__attribute__((address_space(3))) void*)l, 16, 0, 0);
}

// ---------- 1. row normalize + symmetric i8 quantize ----------
__global__ __launch_bounds__(256) void nrm_kernel(const float* __restrict__ feat,
                                                  signed char* __restrict__ zn,
                                                  float* __restrict__ fs) {
    const int row = blockIdx.x;           // 0..8191
    const int tid = threadIdx.x;          // 256, 4 floats each
    const float4 v = reinterpret_cast<const float4*>(feat + (size_t)row * D)[tid];
    float ss = v.x * v.x + v.y * v.y + v.z * v.z + v.w * v.w;
    float am = fmaxf(fmaxf(fabsf(v.x), fabsf(v.y)), fmaxf(fabsf(v.z), fabsf(v.w)));
#pragma unroll
    for (int off = 32; off > 0; off >>= 1) {
        ss += __shfl_down(ss, off);
        am = fmaxf(am, __shfl_down(am, off));
    }
    __shared__ float reds[4], redm[4];
    const int lane = tid & 63, wid = tid >> 6;
    if (lane == 0) { reds[wid] = ss; redm[wid] = am; }
    __syncthreads();
    const float tot = reds[0] + reds[1] + reds[2] + reds[3];
    const float amx = fmaxf(fmaxf(redm[0], redm[1]), fmaxf(redm[2], redm[3]));
    const float nrm = fmaxf(sqrtf(tot), 1e-8f);
    const float wmax = fmaxf(amx / nrm, 1e-12f);
    const float qs = 127.0f / (wmax * nrm);        // w_i * 127/wmax, w_i = v_i/nrm
    int q0 = (int)rintf(fminf(fmaxf(v.x * qs, -127.f), 127.f));
    int q1 = (int)rintf(fminf(fmaxf(v.y * qs, -127.f), 127.f));
    int q2 = (int)rintf(fminf(fmaxf(v.z * qs, -127.f), 127.f));
    int q3 = (int)rintf(fminf(fmaxf(v.w * qs, -127.f), 127.f));
    const int packed = (q0 & 255) | ((q1 & 255) << 8) | ((q2 & 255) << 16) | (q3 << 24);
    reinterpret_cast<int*>(zn)[(size_t)row * (D / 4) + tid] = packed;
    if (tid == 0)
        fs[row] = ((row < NROWS) ? SCALE_U : 1.0f) * wmax * (1.0f / 127.0f);
}

// ---------- 2. Gram (integer), i8 16x16x64 MFMA, scales + LSE in epilogue ----------
// R5-proven 2-phase structure AND R5's exact LDS geometry (measured 0 bank
// conflicts): 128 B rows = 8 x 16B chunks, swizzle phys = chunk ^ (row&7),
// pre-swizzled global source + linear LDS dest (global_load_lds w=16) +
// swizzled ds_read. 128x128 tile, 4 waves (2x2), wave tile 64x64, 4 blocks/CU,
// XCD-aware block swizzle. BKB=128 halves barrier pairs vs BKE=64.
// u_ij = fs1[i]*fs2[j]*dot_int.
__global__ __launch_bounds__(256, 4) void gram_lse_kernel(const signed char* __restrict__ zn,
                                                          const float* __restrict__ fs,
                                                          float* __restrict__ psum,
                                                          float* __restrict__ diag) {
    __shared__ __align__(16) signed char As[BM * BKB];   // 16 KiB
    __shared__ __align__(16) signed char Bs[BM * BKB];   // 16 KiB
    __shared__ float sbuf[BM][2];

    // XCD-aware swizzle: each XCD covers a 16-rowtile x 8-coltile region
    const int bid = blockIdx.x;            // 0..1023
    const int xcd = bid & 7, t = bid >> 3; // t: 0..127 within XCD
    const int rt = (xcd >> 2) * 16 + (t >> 3);   // 0..31
    const int cc = (xcd & 3) * 8 + (t & 7);      // 0..31

    const int tid = threadIdx.x;
    const int lane = tid & 63;
    const int wid  = tid >> 6;        // 0..3
    const int wm = wid >> 1, wn = wid & 1;
    const int l15 = lane & 15, g = lane >> 4;    // frag row/col = l15, k-quarter = g

    // staging: 8 lanes per 128B row; source chunk pre-swizzled so
    // LDS[row][p] = global[row][p ^ (row&7)]
    const int lrow8 = lane >> 3;                 // 0..7 == row&7 within 8-row group
    const int cs    = (lane & 7) ^ lrow8;
    const signed char* gA = zn + (size_t)(rt * BM + lrow8) * D + cs * 16;
    const signed char* gB = zn + (size_t)(NROWS + cc * BM + lrow8) * D + cs * 16;

    i32x4 acc[4][4];
#pragma unroll
    for (int i = 0; i < 4; i++)
#pragma unroll
        for (int j = 0; j < 4; j++) acc[i][j] = (i32x4){0, 0, 0, 0};

    for (int kb = 0; kb < NSLAB; ++kb) {
        __syncthreads();   // previous-iter readers done before overwrite
#pragma unroll
        for (int it = 0; it < 4; ++it) {
            const int r0 = (wid * 4 + it) * 8;         // wave-uniform row base
            gload16(gA + (size_t)r0 * D + kb * BKB, &As[r0 * BKB]);
            gload16(gB + (size_t)r0 * D + kb * BKB, &Bs[r0 * BKB]);
        }
        __syncthreads();   // vmcnt(0) drain: LDS tiles ready

#pragma unroll
        for (int kk = 0; kk < 2; ++kk) {
            i32x4 b[4];
#pragma unroll
            for (int fn = 0; fn < 4; ++fn) {
                const int row = wn * 64 + fn * 16 + l15;
                b[fn] = *reinterpret_cast<const i32x4*>(
                    &Bs[row * BKB + (((kk * 4 + g) ^ (row & 7)) * 16)]);
            }
#pragma unroll
            for (int fr = 0; fr < 4; ++fr) {
                const int row = wm * 64 + fr * 16 + l15;
                const i32x4 a = *reinterpret_cast<const i32x4*>(
                    &As[row * BKB + (((kk * 4 + g) ^ (row & 7)) * 16)]);
#pragma unroll
                for (int fn = 0; fn < 4; ++fn)
                    acc[fr][fn] = __builtin_amdgcn_mfma_i32_16x16x64_i8(a, b[fn], acc[fr][fn], 0, 0, 0);
            }
        }
    }

    // ---- epilogue: apply scales, diag on rt==cc, fused LSE partial sums ----
    // 16x16 C/D layout: col = lane&15, row = (lane>>4)*4 + reg
    float fs2[4];
#pragma unroll
    for (int fn = 0; fn < 4; ++fn)
        fs2[fn] = fs[NROWS + cc * BM + wn * 64 + fn * 16 + l15];

#pragma unroll
    for (int fr = 0; fr < 4; ++fr) {
#pragma unroll
        for (int r = 0; r < 4; ++r) {
            const int rl = wm * 64 + fr * 16 + g * 4 + r;
            const float f1 = fs[rt * BM + rl];
            float s = 0.f;
#pragma unroll
            for (int fn = 0; fn < 4; ++fn) {
                const float u = f1 * fs2[fn] * (float)acc[fr][fn][r];
                s += exp2f(u - LSE_SHIFT);
                if (rt == cc && rl == wn * 64 + fn * 16 + l15)
                    diag[rt * BM + rl] = u;
            }
#pragma unroll
            for (int off = 1; off < 16; off <<= 1) s += __shfl_xor(s, off);
            if (l15 == 0) sbuf[rl][wn] = s;
        }
    }
    __syncthreads();
    if (tid < BM) {
        psum[(size_t)(rt * BM + tid) * NCC + cc] = sbuf[tid][0] + sbuf[tid][1];
    }
}

// ---------- 3. per-row partial combine (diag precomputed in gram) ----------
__global__ __launch_bounds__(256) void rowfinal_kernel(const float* __restrict__ psum,
                                                       const float* __restrict__ diag,
                                                       float* __restrict__ contrib) {
    const int i = blockIdx.x * 256 + threadIdx.x;   // row 0..4095
    float4 ps[8];
#pragma unroll
    for (int q = 0; q < 8; ++q)
        ps[q] = reinterpret_cast<const float4*>(psum + (size_t)i * NCC)[q];
    float s = 0.f;
#pragma unroll
    for (int q = 0; q < 8; ++q) s += (ps[q].x + ps[q].y) + (ps[q].z + ps[q].w);
    contrib[i] = LSE_SHIFT + log2f(s) - diag[i];   // exp2-domain LSE minus u_ii
}

// ---------- 4. deterministic final reduce ----------
__global__ __launch_bounds__(256) void final_kernel(const float* __restrict__ contrib,
                                                    float* __restrict__ out) {
    const int tid = threadIdx.x;
    float s = 0.f;
    for (int j = tid; j < NROWS; j += 256) s += contrib[j];
#pragma unroll
    for (int off = 32; off > 0; off >>= 1) s += __shfl_down(s, off);
    __shared__ float red[4];
    const int lane = tid & 63, wid = tid >> 6;
    if (lane == 0) red[wid] = s;
    __syncthreads();
    if (tid == 0) out[0] = (red[0] + red[1] + red[2] + red[3]) * (LN2 / (float)NROWS);
}

extern "C" void kernel_launch(void* const* d_in, const int* in_sizes, int n_in,
                              void* d_out, int out_size, void* d_ws, size_t ws_size,
                              hipStream_t stream) {
    const float* feat = (const float*)d_in[0];
    signed char* zn = (signed char*)d_ws;
    float* fs      = (float*)((char*)d_ws + 8388608);
    float* psum    = (float*)((char*)d_ws + 8421376);
    float* diag    = (float*)((char*)d_ws + 8945664);
    float* contrib = (float*)((char*)d_ws + 8962048);
    float* out = (float*)d_out;

    nrm_kernel<<<8192, 256, 0, stream>>>(feat, zn, fs);
    gram_lse_kernel<<<1024, 256, 0, stream>>>(zn, fs, psum, diag);
    rowfinal_kernel<<<16, 256, 0, stream>>>(psum, diag, contrib);
    final_kernel<<<1, 256, 0, stream>>>(contrib, out);
}